// Round 5
// baseline (728.273 us; speedup 1.0000x reference)
//
#include <hip/hip_runtime.h>

#define B_ 2048
#define F_ 64
#define DRAW_ 32
#define D_ 15
#define ROWS_ (B_*F_)     /* 131072 rows = (b,f) */
#define BD_ (B_*D_)       /* 30720 rows = (b,d) */

// ---------------------------------------------------------------------------
// k_prep: v[f][k] = sum_j W2[k][j]*dw[114+f*32+j];  C = sum_{f,j} bout[j]*dw[114+f*32+j]
// ---------------------------------------------------------------------------
__global__ __launch_bounds__(256)
void k_prep(const float* __restrict__ W2,      // [128][32]
            const float* __restrict__ bout,    // [32]
            const float* __restrict__ dw,      // [2162]
            float* __restrict__ v,             // [64][128]
            float* __restrict__ Cout) {        // [1]
    int tid = threadIdx.x;
    for (int idx = tid; idx < 64*128; idx += 256) {
        int f = idx >> 7, k = idx & 127;
        float s = 0.f;
        #pragma unroll
        for (int j = 0; j < 32; ++j) s += W2[k*32+j] * dw[114 + f*32 + j];
        v[idx] = s;
    }
    float p = 0.f;
    for (int idx = tid; idx < 2048; idx += 256)
        p += bout[idx & 31] * dw[114 + idx];
    __shared__ float red[256];
    red[tid] = p;
    __syncthreads();
    for (int s = 128; s > 0; s >>= 1) {
        if (tid < s) red[tid] += red[tid+s];
        __syncthreads();
    }
    if (tid == 0) Cout[0] = red[0];
}

// ---------------------------------------------------------------------------
// k_emb: emb = x@embW + embB (stored in both [b,f,d] and [b,d,f] layouts);
//        liner[row] = x@linW + linB
// ---------------------------------------------------------------------------
__global__ __launch_bounds__(256)
void k_emb(const float* __restrict__ x,        // [B,F,32]
           const float* __restrict__ embW,     // [32][15]
           const float* __restrict__ embB,     // [15]
           const float* __restrict__ linW,     // [32]
           const float* __restrict__ linB,     // [1]
           float* __restrict__ emb_bfd,        // [ROWS][15]
           float* __restrict__ emb_bdf,        // [BD][64]
           float* __restrict__ liner) {        // [ROWS]
    __shared__ float xL[256*33];   // 33.8 KB
    __shared__ float wL[32*15];
    __shared__ float lwL[32];
    int tid = threadIdx.x;
    for (int i = tid; i < 480; i += 256) wL[i] = embW[i];
    if (tid < 32) lwL[tid] = linW[tid];
    // coalesced stage of 256 rows x 32 floats (pad 33 -> conflict-free reads)
    const float4* xs = (const float4*)(x + (size_t)blockIdx.x * 256 * 32);
    #pragma unroll
    for (int j = 0; j < 8; ++j) {
        int f4 = tid + 256*j;
        float4 val = xs[f4];
        int row = f4 >> 3, k0 = (f4 & 7) << 2;
        xL[row*33 + k0]     = val.x;
        xL[row*33 + k0 + 1] = val.y;
        xL[row*33 + k0 + 2] = val.z;
        xL[row*33 + k0 + 3] = val.w;
    }
    __syncthreads();
    int row = blockIdx.x * 256 + tid;
    float acc[15];
    #pragma unroll
    for (int d2 = 0; d2 < 15; ++d2) acc[d2] = 0.f;
    float lin = 0.f;
    #pragma unroll
    for (int k = 0; k < 32; ++k) {
        float xv = xL[tid*33 + k];
        #pragma unroll
        for (int d2 = 0; d2 < 15; ++d2) acc[d2] += xv * wL[k*15 + d2];
        lin += xv * lwL[k];
    }
    int b = row >> 6, f = row & 63;
    #pragma unroll
    for (int d2 = 0; d2 < 15; ++d2) {
        float val = acc[d2] + embB[d2];
        emb_bfd[(size_t)row*15 + d2] = val;
        emb_bdf[(size_t)(b*15 + d2)*64 + f] = val;   // coalesced over f within wave
    }
    liner[row] = lin + linB[0];
}

// ---------------------------------------------------------------------------
// k_dnn: fused  h1=relu(emb@W0+b0) -> h2=relu(h1@W1+b1) -> rdnn=h2 . v[f]
// (unchanged this round; counters next round once k_cin stops dominating)
// ---------------------------------------------------------------------------
__global__ __launch_bounds__(256)
void k_dnn(const float* __restrict__ emb_bfd,  // [ROWS][15]
           const float* __restrict__ W0,       // [15][256]
           const float* __restrict__ b0,       // [256]
           const float* __restrict__ W1,       // [256][128]
           const float* __restrict__ b1,       // [128]
           const float* __restrict__ v,        // [64][128]
           float* __restrict__ rdnn) {         // [ROWS]
    __shared__ float embL[128*16];
    __shared__ float w0L[15*256];
    __shared__ float h1L[128*33];   // chunk of 32 h1-cols, pad 33
    __shared__ float w1L[32*130];   // chunk of 32 W1-rows, pad 130
    int tid = threadIdx.x;
    int rows0 = blockIdx.x * 128;

    for (int i = tid; i < 128*15; i += 256) {
        int r = i / 15, q = i - r*15;
        embL[r*16+q] = emb_bfd[(size_t)rows0*15 + i];
    }
    for (int i = tid; i < 15*256; i += 256) w0L[i] = W0[i];
    __syncthreads();

    float acc[8][8];
    #pragma unroll
    for (int i = 0; i < 8; ++i)
        #pragma unroll
        for (int j = 0; j < 8; ++j) acc[i][j] = 0.f;

    int c2 = tid & 31, rg = tid >> 5;   // layer-1 compute map
    int ct = tid & 15, rt = tid >> 4;   // GEMM map: rows rt*8..+7, cols ct+16*j

    for (int kc = 0; kc < 8; ++kc) {
        for (int i = tid; i < 4096; i += 256) {
            int k = i >> 7, c = i & 127;
            w1L[k*130 + c] = W1[kc*4096 + i];
        }
        float bb = b0[kc*32 + c2];
        #pragma unroll
        for (int r16 = 0; r16 < 16; ++r16) {
            int r = rg*16 + r16;
            float s = bb;
            #pragma unroll
            for (int q = 0; q < 15; ++q)
                s += embL[r*16+q] * w0L[q*256 + kc*32 + c2];
            h1L[r*33 + c2] = fmaxf(s, 0.f);
        }
        __syncthreads();
        #pragma unroll 4
        for (int k = 0; k < 32; ++k) {
            float a[8], w[8];
            #pragma unroll
            for (int i = 0; i < 8; ++i) a[i] = h1L[(rt*8+i)*33 + k];
            #pragma unroll
            for (int j = 0; j < 8; ++j) w[j] = w1L[k*130 + ct + 16*j];
            #pragma unroll
            for (int i = 0; i < 8; ++i)
                #pragma unroll
                for (int j = 0; j < 8; ++j) acc[i][j] += a[i]*w[j];
        }
        __syncthreads();
    }
    float b1v[8];
    #pragma unroll
    for (int j = 0; j < 8; ++j) b1v[j] = b1[ct + 16*j];
    #pragma unroll
    for (int i = 0; i < 8; ++i) {
        int lrow = rt*8 + i;
        int f = (rows0 + lrow) & 63;
        float p = 0.f;
        #pragma unroll
        for (int j = 0; j < 8; ++j) {
            float h2 = fmaxf(acc[i][j] + b1v[j], 0.f);
            p += h2 * v[f*128 + ct + 16*j];
        }
        p += __shfl_xor(p, 1, 64);
        p += __shfl_xor(p, 2, 64);
        p += __shfl_xor(p, 4, 64);
        p += __shfl_xor(p, 8, 64);
        if (ct == 0) rdnn[rows0 + lrow] = p;
    }
}

// ---------------------------------------------------------------------------
// k_cin v2: 64 rows/block, 256 threads = 8 rt-groups x 32 ct.
// Thread tile: 8 rows x 20 cols (fields ct, ct+32 -> cols f*10+n).
// LDS: EL = E^T [g][row] pad 68 (b128 fragment loads);
//      AB = union{ A-chunk [f][162|102] (b64 reads, 2-way max) , PB partials [row][162] };
//      HT = h^T [n][row] pad 68.
// Epilogue: 1 shfl_xor(16) level + LDS 2-phase reduce (replaces 5-level shuffle).
// Predicted: 229 -> 40-55 us, VALUBusy 60-75%.
// ---------------------------------------------------------------------------
__global__ __launch_bounds__(256, 2)
void k_cin(const float* __restrict__ emb_bdf,  // [BD][64]
           const float* __restrict__ cw0,      // [4096][10]
           const float* __restrict__ cw1,      // [640][10]
           const float* __restrict__ cw2,
           const float* __restrict__ cw3,
           const float* __restrict__ cw4,
           float* __restrict__ hi_ws) {        // [5][BD][10]
    __shared__ float EL[64*68];    // 17.0 KB  E^T[field][row]
    __shared__ float AB[64*162];   // 41.5 KB  A-chunk / partial buffer (union)
    __shared__ float HT[10*68];    //  2.7 KB  h^T[n][row]
    int tid = threadIdx.x;
    int rt = tid >> 5, ct = tid & 31;
    int rows0 = blockIdx.x * 64;
    const int fp1 = ct, fp2 = ct + 32;

    // stage E^T: coalesced global read, transpose into EL[f*68 + r]
    {
        int f = tid & 63, rb = tid >> 6;
        #pragma unroll
        for (int it = 0; it < 16; ++it) {
            int r = rb + it*4;
            EL[f*68 + r] = emb_bdf[(size_t)(rows0 + r)*64 + f];
        }
    }

    float acc[8][20];
    #pragma unroll
    for (int i = 0; i < 8; ++i)
        #pragma unroll
        for (int j = 0; j < 20; ++j) acc[i][j] = 0.f;

    // epilogue macro: acc -> pn (in place) -> 1 shuffle level -> PB in AB -> reduce
    #define CIN_EPI(LIDX)                                                       \
    {                                                                           \
        __syncthreads(); /* GEMM reads of AB done; AB becomes PB */             \
        float ef1[8], ef2[8];                                                   \
        *(float4*)&ef1[0] = *(const float4*)&EL[fp1*68 + rt*8];                 \
        *(float4*)&ef1[4] = *(const float4*)&EL[fp1*68 + rt*8 + 4];             \
        *(float4*)&ef2[0] = *(const float4*)&EL[fp2*68 + rt*8];                 \
        *(float4*)&ef2[4] = *(const float4*)&EL[fp2*68 + rt*8 + 4];             \
        _Pragma("unroll")                                                       \
        for (int i = 0; i < 8; ++i) {                                           \
            _Pragma("unroll")                                                   \
            for (int n = 0; n < 10; ++n) {                                      \
                float p = ef1[i]*acc[i][n] + ef2[i]*acc[i][10+n];               \
                p += __shfl_xor(p, 16, 64);                                     \
                acc[i][n] = p;                                                  \
            }                                                                   \
        }                                                                       \
        if (ct < 16) {                                                          \
            _Pragma("unroll")                                                   \
            for (int i = 0; i < 8; ++i) {                                       \
                float2* pb = (float2*)&AB[(rt*8 + i)*162 + ct*10];              \
                _Pragma("unroll")                                               \
                for (int t = 0; t < 5; ++t)                                     \
                    pb[t] = make_float2(acc[i][t*2], acc[i][t*2+1]);            \
            }                                                                   \
        }                                                                       \
        __syncthreads();                                                        \
        for (int o = tid; o < 640; o += 256) {                                  \
            int r2 = o / 10, n2 = o - r2*10;                                    \
            float s = 0.f;                                                      \
            _Pragma("unroll")                                                   \
            for (int c2 = 0; c2 < 16; ++c2) s += AB[r2*162 + c2*10 + n2];       \
            HT[n2*68 + r2] = s;                                                 \
            hi_ws[((size_t)(LIDX)*BD_ + rows0 + r2)*10 + n2] = s;               \
        }                                                                       \
        __syncthreads();                                                        \
    }

    // ---- layer 0: K=64 over g, 4 staged chunks of 16 ----
    for (int c = 0; c < 4; ++c) {
        __syncthreads();   // covers EL stage (c=0) and prior GEMM reads of AB
        {   // stage AB[f*162 + s] = cw0[f*640 + c*160 + s], s in [0,160): contiguous
            int f = tid >> 2, q = tid & 3;
            const float4* src = (const float4*)(cw0 + f*640 + c*160);
            float2* dst = (float2*)&AB[f*162];
            #pragma unroll
            for (int t = 0; t < 10; ++t) {
                int idx = q + t*4;
                float4 vv = src[idx];
                dst[idx*2]     = make_float2(vv.x, vv.y);
                dst[idx*2 + 1] = make_float2(vv.z, vv.w);
            }
        }
        __syncthreads();
        #pragma unroll
        for (int gl = 0; gl < 16; ++gl) {
            int g = c*16 + gl;
            float e8[8];
            *(float4*)&e8[0] = *(const float4*)&EL[g*68 + rt*8];
            *(float4*)&e8[4] = *(const float4*)&EL[g*68 + rt*8 + 4];
            float2 a1[5], a2[5];
            #pragma unroll
            for (int t = 0; t < 5; ++t) {
                a1[t] = *(const float2*)&AB[fp1*162 + gl*10 + t*2];
                a2[t] = *(const float2*)&AB[fp2*162 + gl*10 + t*2];
            }
            #pragma unroll
            for (int i = 0; i < 8; ++i) {
                float e = e8[i];
                #pragma unroll
                for (int t = 0; t < 5; ++t) {
                    acc[i][t*2]      += e * a1[t].x;
                    acc[i][t*2+1]    += e * a1[t].y;
                    acc[i][10+t*2]   += e * a2[t].x;
                    acc[i][10+t*2+1] += e * a2[t].y;
                }
            }
        }
    }
    CIN_EPI(0)

    // ---- layers 1..4: K=10 over g ----
    for (int l = 1; l < 5; ++l) {
        const float* cw = (l==1) ? cw1 : (l==2) ? cw2 : (l==3) ? cw3 : cw4;
        {   // stage AB[f*102 + s] = cw[f*100 + s], s in [0,100): contiguous
            int f = tid >> 2, q = tid & 3;
            const float4* src = (const float4*)(cw + f*100);
            float2* dst = (float2*)&AB[f*102];
            for (int idx = q; idx < 25; idx += 4) {
                float4 vv = src[idx];
                dst[idx*2]     = make_float2(vv.x, vv.y);
                dst[idx*2 + 1] = make_float2(vv.z, vv.w);
            }
        }
        #pragma unroll
        for (int i = 0; i < 8; ++i)
            #pragma unroll
            for (int j = 0; j < 20; ++j) acc[i][j] = 0.f;
        __syncthreads();
        #pragma unroll
        for (int g = 0; g < 10; ++g) {
            float e8[8];
            *(float4*)&e8[0] = *(const float4*)&HT[g*68 + rt*8];
            *(float4*)&e8[4] = *(const float4*)&HT[g*68 + rt*8 + 4];
            float2 a1[5], a2[5];
            #pragma unroll
            for (int t = 0; t < 5; ++t) {
                a1[t] = *(const float2*)&AB[fp1*102 + g*10 + t*2];
                a2[t] = *(const float2*)&AB[fp2*102 + g*10 + t*2];
            }
            #pragma unroll
            for (int i = 0; i < 8; ++i) {
                float e = e8[i];
                #pragma unroll
                for (int t = 0; t < 5; ++t) {
                    acc[i][t*2]      += e * a1[t].x;
                    acc[i][t*2+1]    += e * a1[t].y;
                    acc[i][10+t*2]   += e * a2[t].x;
                    acc[i][10+t*2+1] += e * a2[t].y;
                }
            }
        }
        CIN_EPI(l)
    }
    #undef CIN_EPI
}

// ---------------------------------------------------------------------------
// k_combine: out[b] = sum_f liner*dw + sum cin*dw + sum_f rdnn + db + C
// ---------------------------------------------------------------------------
__global__ __launch_bounds__(64)
void k_combine(const float* __restrict__ liner,   // [ROWS]
               const float* __restrict__ rdnn,    // [ROWS]
               const float* __restrict__ hi_ws,   // [5][BD][10]
               const float* __restrict__ dw,      // [2162]
               const float* __restrict__ db,      // [1]
               const float* __restrict__ Cc,      // [1]
               float* __restrict__ out) {         // [B]
    int b = blockIdx.x, t = threadIdx.x;
    float s = liner[b*64+t]*dw[t] + rdnn[b*64+t];
    for (int i = t; i < 750; i += 64) {
        int ld = i / 10, n = i - ld*10;
        int l = ld / 15, d = ld - l*15;
        s += hi_ws[((size_t)l*BD_ + b*15 + d)*10 + n] * dw[64 + l*10 + n];
    }
    #pragma unroll
    for (int m = 1; m < 64; m <<= 1) s += __shfl_xor(s, m, 64);
    if (t == 0) out[b] = s + db[0] + Cc[0];
}

// ---------------------------------------------------------------------------
extern "C" void kernel_launch(void* const* d_in, const int* in_sizes, int n_in,
                              void* d_out, int out_size, void* d_ws, size_t ws_size,
                              hipStream_t stream) {
    const float* x    = (const float*)d_in[0];
    const float* embW = (const float*)d_in[1];
    const float* embB = (const float*)d_in[2];
    const float* linW = (const float*)d_in[3];
    const float* linB = (const float*)d_in[4];
    const float* W0   = (const float*)d_in[5];
    const float* b0   = (const float*)d_in[6];
    const float* W1   = (const float*)d_in[7];
    const float* b1   = (const float*)d_in[8];
    const float* W2   = (const float*)d_in[9];
    const float* bout = (const float*)d_in[10];
    const float* cw0  = (const float*)d_in[11];
    const float* cw1  = (const float*)d_in[12];
    const float* cw2  = (const float*)d_in[13];
    const float* cw3  = (const float*)d_in[14];
    const float* cw4  = (const float*)d_in[15];
    const float* dw   = (const float*)d_in[16];
    const float* db   = (const float*)d_in[17];

    float* ws = (float*)d_ws;
    float* emb_bfd = ws;                   // 1,966,080 floats
    float* emb_bdf = ws + 1966080;         // 1,966,080
    float* liner   = ws + 3932160;         //   131,072
    float* rdnn    = ws + 4063232;         //   131,072
    float* hi_ws   = ws + 4194304;         // 1,536,000
    float* v       = ws + 5730304;         //     8,192
    float* Cc      = ws + 5738496;         //         1  (total ~22.96 MB)
    float* out = (float*)d_out;

    k_prep<<<1, 256, 0, stream>>>(W2, bout, dw, v, Cc);
    k_emb<<<512, 256, 0, stream>>>(x, embW, embB, linW, linB, emb_bfd, emb_bdf, liner);
    k_dnn<<<1024, 256, 0, stream>>>(emb_bfd, W0, b0, W1, b1, v, rdnn);
    k_cin<<<480, 256, 0, stream>>>(emb_bdf, cw0, cw1, cw2, cw3, cw4, hi_ws);
    k_combine<<<2048, 64, 0, stream>>>(liner, rdnn, hi_ws, dw, db, Cc, out);
}

// Round 6
// 429.793 us; speedup vs baseline: 1.6945x; 1.6945x over previous
//
#include <hip/hip_runtime.h>

#define B_ 2048
#define F_ 64
#define DRAW_ 32
#define D_ 15
#define ROWS_ (B_*F_)     /* 131072 rows = (b,f) */
#define BD_ (B_*D_)       /* 30720 rows = (b,d) */

// ---------------------------------------------------------------------------
// k_prep: v[f][k] = sum_j W2[k][j]*dw[114+f*32+j];  C = sum_{f,j} bout[j]*dw[114+f*32+j]
// ---------------------------------------------------------------------------
__global__ __launch_bounds__(256)
void k_prep(const float* __restrict__ W2,      // [128][32]
            const float* __restrict__ bout,    // [32]
            const float* __restrict__ dw,      // [2162]
            float* __restrict__ v,             // [64][128]
            float* __restrict__ Cout) {        // [1]
    int tid = threadIdx.x;
    for (int idx = tid; idx < 64*128; idx += 256) {
        int f = idx >> 7, k = idx & 127;
        float s = 0.f;
        #pragma unroll
        for (int j = 0; j < 32; ++j) s += W2[k*32+j] * dw[114 + f*32 + j];
        v[idx] = s;
    }
    float p = 0.f;
    for (int idx = tid; idx < 2048; idx += 256)
        p += bout[idx & 31] * dw[114 + idx];
    __shared__ float red[256];
    red[tid] = p;
    __syncthreads();
    for (int s = 128; s > 0; s >>= 1) {
        if (tid < s) red[tid] += red[tid+s];
        __syncthreads();
    }
    if (tid == 0) Cout[0] = red[0];
}

// ---------------------------------------------------------------------------
// k_emb: emb = x@embW + embB (stored in both [b,f,d] and [b,d,f] layouts);
//        liner[row] = x@linW + linB
// ---------------------------------------------------------------------------
__global__ __launch_bounds__(256)
void k_emb(const float* __restrict__ x,        // [B,F,32]
           const float* __restrict__ embW,     // [32][15]
           const float* __restrict__ embB,     // [15]
           const float* __restrict__ linW,     // [32]
           const float* __restrict__ linB,     // [1]
           float* __restrict__ emb_bfd,        // [ROWS][15]
           float* __restrict__ emb_bdf,        // [BD][64]
           float* __restrict__ liner) {        // [ROWS]
    __shared__ float xL[256*33];   // 33.8 KB
    __shared__ float wL[32*15];
    __shared__ float lwL[32];
    int tid = threadIdx.x;
    for (int i = tid; i < 480; i += 256) wL[i] = embW[i];
    if (tid < 32) lwL[tid] = linW[tid];
    // coalesced stage of 256 rows x 32 floats (pad 33 -> conflict-free reads)
    const float4* xs = (const float4*)(x + (size_t)blockIdx.x * 256 * 32);
    #pragma unroll
    for (int j = 0; j < 8; ++j) {
        int f4 = tid + 256*j;
        float4 val = xs[f4];
        int row = f4 >> 3, k0 = (f4 & 7) << 2;
        xL[row*33 + k0]     = val.x;
        xL[row*33 + k0 + 1] = val.y;
        xL[row*33 + k0 + 2] = val.z;
        xL[row*33 + k0 + 3] = val.w;
    }
    __syncthreads();
    int row = blockIdx.x * 256 + tid;
    float acc[15];
    #pragma unroll
    for (int d2 = 0; d2 < 15; ++d2) acc[d2] = 0.f;
    float lin = 0.f;
    #pragma unroll
    for (int k = 0; k < 32; ++k) {
        float xv = xL[tid*33 + k];
        #pragma unroll
        for (int d2 = 0; d2 < 15; ++d2) acc[d2] += xv * wL[k*15 + d2];
        lin += xv * lwL[k];
    }
    int b = row >> 6, f = row & 63;
    #pragma unroll
    for (int d2 = 0; d2 < 15; ++d2) {
        float val = acc[d2] + embB[d2];
        emb_bfd[(size_t)row*15 + d2] = val;
        emb_bdf[(size_t)(b*15 + d2)*64 + f] = val;   // coalesced over f within wave
    }
    liner[row] = lin + linB[0];
}

// ---------------------------------------------------------------------------
// k_dnn: fused  h1=relu(emb@W0+b0) -> h2=relu(h1@W1+b1) -> rdnn=h2 . v[f]
// (unchanged this round; will surface in counters once k_cin stops dominating)
// ---------------------------------------------------------------------------
__global__ __launch_bounds__(256)
void k_dnn(const float* __restrict__ emb_bfd,  // [ROWS][15]
           const float* __restrict__ W0,       // [15][256]
           const float* __restrict__ b0,       // [256]
           const float* __restrict__ W1,       // [256][128]
           const float* __restrict__ b1,       // [128]
           const float* __restrict__ v,        // [64][128]
           float* __restrict__ rdnn) {         // [ROWS]
    __shared__ float embL[128*16];
    __shared__ float w0L[15*256];
    __shared__ float h1L[128*33];   // chunk of 32 h1-cols, pad 33
    __shared__ float w1L[32*130];   // chunk of 32 W1-rows, pad 130
    int tid = threadIdx.x;
    int rows0 = blockIdx.x * 128;

    for (int i = tid; i < 128*15; i += 256) {
        int r = i / 15, q = i - r*15;
        embL[r*16+q] = emb_bfd[(size_t)rows0*15 + i];
    }
    for (int i = tid; i < 15*256; i += 256) w0L[i] = W0[i];
    __syncthreads();

    float acc[8][8];
    #pragma unroll
    for (int i = 0; i < 8; ++i)
        #pragma unroll
        for (int j = 0; j < 8; ++j) acc[i][j] = 0.f;

    int c2 = tid & 31, rg = tid >> 5;   // layer-1 compute map
    int ct = tid & 15, rt = tid >> 4;   // GEMM map: rows rt*8..+7, cols ct+16*j

    for (int kc = 0; kc < 8; ++kc) {
        for (int i = tid; i < 4096; i += 256) {
            int k = i >> 7, c = i & 127;
            w1L[k*130 + c] = W1[kc*4096 + i];
        }
        float bb = b0[kc*32 + c2];
        #pragma unroll
        for (int r16 = 0; r16 < 16; ++r16) {
            int r = rg*16 + r16;
            float s = bb;
            #pragma unroll
            for (int q = 0; q < 15; ++q)
                s += embL[r*16+q] * w0L[q*256 + kc*32 + c2];
            h1L[r*33 + c2] = fmaxf(s, 0.f);
        }
        __syncthreads();
        #pragma unroll 4
        for (int k = 0; k < 32; ++k) {
            float a[8], w[8];
            #pragma unroll
            for (int i = 0; i < 8; ++i) a[i] = h1L[(rt*8+i)*33 + k];
            #pragma unroll
            for (int j = 0; j < 8; ++j) w[j] = w1L[k*130 + ct + 16*j];
            #pragma unroll
            for (int i = 0; i < 8; ++i)
                #pragma unroll
                for (int j = 0; j < 8; ++j) acc[i][j] += a[i]*w[j];
        }
        __syncthreads();
    }
    float b1v[8];
    #pragma unroll
    for (int j = 0; j < 8; ++j) b1v[j] = b1[ct + 16*j];
    #pragma unroll
    for (int i = 0; i < 8; ++i) {
        int lrow = rt*8 + i;
        int f = (rows0 + lrow) & 63;
        float p = 0.f;
        #pragma unroll
        for (int j = 0; j < 8; ++j) {
            float h2 = fmaxf(acc[i][j] + b1v[j], 0.f);
            p += h2 * v[f*128 + ct + 16*j];
        }
        p += __shfl_xor(p, 1, 64);
        p += __shfl_xor(p, 2, 64);
        p += __shfl_xor(p, 4, 64);
        p += __shfl_xor(p, 8, 64);
        if (ct == 0) rdnn[rows0 + lrow] = p;
    }
}

// ---------------------------------------------------------------------------
// k_cin v3: 32 rows/block, 256 threads = 8 rt x 32 ct; tile 4 rows x 20 cols
// (fields ct, ct+32). acc[4][20]=80 regs (v1-proven budget, NO spill).
// Vector LDS: E^T [f][36] b128-broadcast reads; A [f][82|102] contiguous rows,
// b64 reads (2-way max); epilogue = 1 shfl_xor(16) + 16-partial LDS reduce
// (PB aliased into AB). LDS 36.8 KB -> 4 blocks/CU.
// Predicted: 229 -> 35-70 us, WRITE_SIZE ~6 MB (spill gone), VALUBusy 50-75%.
// ---------------------------------------------------------------------------
__global__ __launch_bounds__(256)
void k_cin(const float* __restrict__ emb_bdf,  // [BD][64]
           const float* __restrict__ cw0,      // [4096][10]
           const float* __restrict__ cw1,      // [640][10]
           const float* __restrict__ cw2,
           const float* __restrict__ cw3,
           const float* __restrict__ cw4,
           float* __restrict__ hi_ws) {        // [5][BD][10]
    __shared__ float EL[64*36];    //  9.2 KB  E^T[field][row], rows 0..31
    __shared__ float AB[64*102];   // 26.1 KB  A-chunk [f][80|100+2] / PB [32][162]
    __shared__ float HT[10*36];    //  1.4 KB  h^T[n][row]
    int tid = threadIdx.x;
    int rt = tid >> 5, ct = tid & 31;
    int rows0 = blockIdx.x * 32;
    const int fp1 = ct, fp2 = ct + 32;

    // stage E^T: coalesced global over f, transpose into EL[f*36 + r]
    {
        int f = tid & 63, rb = tid >> 6;
        #pragma unroll
        for (int it = 0; it < 8; ++it) {
            int r = rb + it*4;
            EL[f*36 + r] = emb_bdf[(size_t)(rows0 + r)*64 + f];
        }
    }

    float acc[4][20];
    #pragma unroll
    for (int i = 0; i < 4; ++i)
        #pragma unroll
        for (int j = 0; j < 20; ++j) acc[i][j] = 0.f;

    // epilogue: contract acc with E over this thread's 2 fields, fold ct^16
    // partner via 1 shuffle, LDS-reduce the 16 remaining partials.
    #define CIN_EPI(LIDX)                                                       \
    {                                                                           \
        __syncthreads(); /* k-loop reads of AB done; AB becomes PB */           \
        float ef1[4], ef2[4];                                                   \
        *(float4*)&ef1[0] = *(const float4*)&EL[fp1*36 + rt*4];                 \
        *(float4*)&ef2[0] = *(const float4*)&EL[fp2*36 + rt*4];                 \
        _Pragma("unroll")                                                       \
        for (int i = 0; i < 4; ++i) {                                           \
            _Pragma("unroll")                                                   \
            for (int n = 0; n < 10; ++n) {                                      \
                float p = ef1[i]*acc[i][n] + ef2[i]*acc[i][10+n];               \
                p += __shfl_xor(p, 16, 64);                                     \
                acc[i][n] = p;                                                  \
            }                                                                   \
        }                                                                       \
        if (ct < 16) {                                                          \
            _Pragma("unroll")                                                   \
            for (int i = 0; i < 4; ++i) {                                       \
                float2* pb = (float2*)&AB[(rt*4 + i)*162 + ct*10];              \
                _Pragma("unroll")                                               \
                for (int t = 0; t < 5; ++t)                                     \
                    pb[t] = make_float2(acc[i][t*2], acc[i][t*2+1]);            \
            }                                                                   \
        }                                                                       \
        __syncthreads();                                                        \
        for (int o = tid; o < 320; o += 256) {                                  \
            int r2 = o / 10, n2 = o - r2*10;                                    \
            float s = 0.f;                                                      \
            _Pragma("unroll")                                                   \
            for (int c2 = 0; c2 < 16; ++c2) s += AB[r2*162 + c2*10 + n2];       \
            HT[n2*36 + r2] = s;                                                 \
            hi_ws[((size_t)(LIDX)*BD_ + rows0 + r2)*10 + n2] = s;               \
        }                                                                       \
    }

    // ---- layer 0: K=64 over g, 8 staged chunks of 8 ----
    for (int c = 0; c < 8; ++c) {
        __syncthreads();   // covers EL stage (c=0) / prior k-loop reads of AB
        {   // AB[f*82 + s] = cw0[f*640 + c*80 + s], s in [0,80): contiguous
            int f = tid >> 2, q = tid & 3;
            const float4* src = (const float4*)(cw0 + f*640 + c*80);
            #pragma unroll
            for (int t = 0; t < 5; ++t) {
                int idx = q + t*4;
                float4 vv = src[idx];
                float2* dst = (float2*)&AB[f*82 + idx*4];
                dst[0] = make_float2(vv.x, vv.y);
                dst[1] = make_float2(vv.z, vv.w);
            }
        }
        __syncthreads();
        #pragma unroll
        for (int gl = 0; gl < 8; ++gl) {
            int g = c*8 + gl;
            float e4[4];
            *(float4*)&e4[0] = *(const float4*)&EL[g*36 + rt*4];
            float2 a1[5];
            #pragma unroll
            for (int t = 0; t < 5; ++t)
                a1[t] = *(const float2*)&AB[fp1*82 + gl*10 + t*2];
            #pragma unroll
            for (int i = 0; i < 4; ++i) {
                float e = e4[i];
                #pragma unroll
                for (int t = 0; t < 5; ++t) {
                    acc[i][t*2]   += e * a1[t].x;
                    acc[i][t*2+1] += e * a1[t].y;
                }
            }
            float2 a2[5];
            #pragma unroll
            for (int t = 0; t < 5; ++t)
                a2[t] = *(const float2*)&AB[fp2*82 + gl*10 + t*2];
            #pragma unroll
            for (int i = 0; i < 4; ++i) {
                float e = e4[i];
                #pragma unroll
                for (int t = 0; t < 5; ++t) {
                    acc[i][10+t*2]   += e * a2[t].x;
                    acc[i][10+t*2+1] += e * a2[t].y;
                }
            }
        }
    }
    CIN_EPI(0)

    // ---- layers 1..4: K=10 over g ----
    for (int l = 1; l < 5; ++l) {
        const float* cw = (l==1) ? cw1 : (l==2) ? cw2 : (l==3) ? cw3 : cw4;
        __syncthreads();   // PB reads done; HT writes visible
        {   // AB[f*102 + s] = cw[f*100 + s], s in [0,100): contiguous
            int f = tid >> 2, q = tid & 3;
            const float4* src = (const float4*)(cw + f*100);
            for (int idx = q; idx < 25; idx += 4) {
                float4 vv = src[idx];
                float2* dst = (float2*)&AB[f*102 + idx*4];
                dst[0] = make_float2(vv.x, vv.y);
                dst[1] = make_float2(vv.z, vv.w);
            }
        }
        #pragma unroll
        for (int i = 0; i < 4; ++i)
            #pragma unroll
            for (int j = 0; j < 20; ++j) acc[i][j] = 0.f;
        __syncthreads();
        #pragma unroll
        for (int g = 0; g < 10; ++g) {
            float e4[4];
            *(float4*)&e4[0] = *(const float4*)&HT[g*36 + rt*4];
            float2 a1[5];
            #pragma unroll
            for (int t = 0; t < 5; ++t)
                a1[t] = *(const float2*)&AB[fp1*102 + g*10 + t*2];
            #pragma unroll
            for (int i = 0; i < 4; ++i) {
                float e = e4[i];
                #pragma unroll
                for (int t = 0; t < 5; ++t) {
                    acc[i][t*2]   += e * a1[t].x;
                    acc[i][t*2+1] += e * a1[t].y;
                }
            }
            float2 a2[5];
            #pragma unroll
            for (int t = 0; t < 5; ++t)
                a2[t] = *(const float2*)&AB[fp2*102 + g*10 + t*2];
            #pragma unroll
            for (int i = 0; i < 4; ++i) {
                float e = e4[i];
                #pragma unroll
                for (int t = 0; t < 5; ++t) {
                    acc[i][10+t*2]   += e * a2[t].x;
                    acc[i][10+t*2+1] += e * a2[t].y;
                }
            }
        }
        CIN_EPI(l)
    }
    #undef CIN_EPI
}

// ---------------------------------------------------------------------------
// k_combine: out[b] = sum_f liner*dw + sum cin*dw + sum_f rdnn + db + C
// ---------------------------------------------------------------------------
__global__ __launch_bounds__(64)
void k_combine(const float* __restrict__ liner,   // [ROWS]
               const float* __restrict__ rdnn,    // [ROWS]
               const float* __restrict__ hi_ws,   // [5][BD][10]
               const float* __restrict__ dw,      // [2162]
               const float* __restrict__ db,      // [1]
               const float* __restrict__ Cc,      // [1]
               float* __restrict__ out) {         // [B]
    int b = blockIdx.x, t = threadIdx.x;
    float s = liner[b*64+t]*dw[t] + rdnn[b*64+t];
    for (int i = t; i < 750; i += 64) {
        int ld = i / 10, n = i - ld*10;
        int l = ld / 15, d = ld - l*15;
        s += hi_ws[((size_t)l*BD_ + b*15 + d)*10 + n] * dw[64 + l*10 + n];
    }
    #pragma unroll
    for (int m = 1; m < 64; m <<= 1) s += __shfl_xor(s, m, 64);
    if (t == 0) out[b] = s + db[0] + Cc[0];
}

// ---------------------------------------------------------------------------
extern "C" void kernel_launch(void* const* d_in, const int* in_sizes, int n_in,
                              void* d_out, int out_size, void* d_ws, size_t ws_size,
                              hipStream_t stream) {
    const float* x    = (const float*)d_in[0];
    const float* embW = (const float*)d_in[1];
    const float* embB = (const float*)d_in[2];
    const float* linW = (const float*)d_in[3];
    const float* linB = (const float*)d_in[4];
    const float* W0   = (const float*)d_in[5];
    const float* b0   = (const float*)d_in[6];
    const float* W1   = (const float*)d_in[7];
    const float* b1   = (const float*)d_in[8];
    const float* W2   = (const float*)d_in[9];
    const float* bout = (const float*)d_in[10];
    const float* cw0  = (const float*)d_in[11];
    const float* cw1  = (const float*)d_in[12];
    const float* cw2  = (const float*)d_in[13];
    const float* cw3  = (const float*)d_in[14];
    const float* cw4  = (const float*)d_in[15];
    const float* dw   = (const float*)d_in[16];
    const float* db   = (const float*)d_in[17];

    float* ws = (float*)d_ws;
    float* emb_bfd = ws;                   // 1,966,080 floats
    float* emb_bdf = ws + 1966080;         // 1,966,080
    float* liner   = ws + 3932160;         //   131,072
    float* rdnn    = ws + 4063232;         //   131,072
    float* hi_ws   = ws + 4194304;         // 1,536,000
    float* v       = ws + 5730304;         //     8,192
    float* Cc      = ws + 5738496;         //         1  (total ~22.96 MB)
    float* out = (float*)d_out;

    k_prep<<<1, 256, 0, stream>>>(W2, bout, dw, v, Cc);
    k_emb<<<512, 256, 0, stream>>>(x, embW, embB, linW, linB, emb_bfd, emb_bdf, liner);
    k_dnn<<<1024, 256, 0, stream>>>(emb_bfd, W0, b0, W1, b1, v, rdnn);
    k_cin<<<960, 256, 0, stream>>>(emb_bdf, cw0, cw1, cw2, cw3, cw4, hi_ws);
    k_combine<<<2048, 64, 0, stream>>>(liner, rdnn, hi_ws, dw, db, Cc, out);
}

// Round 8
// 381.032 us; speedup vs baseline: 1.9113x; 1.1280x over previous
//
#include <hip/hip_runtime.h>

#define B_ 2048
#define F_ 64
#define DRAW_ 32
#define D_ 15
#define ROWS_ (B_*F_)     /* 131072 rows = (b,f) */
#define BD_ (B_*D_)       /* 30720 rows = (b,d) */

// ---------------------------------------------------------------------------
// k_prep: v[f][k] = sum_j W2[k][j]*dw[114+f*32+j];  C = sum_{f,j} bout[j]*dw[114+f*32+j]
// ---------------------------------------------------------------------------
__global__ __launch_bounds__(256)
void k_prep(const float* __restrict__ W2,      // [128][32]
            const float* __restrict__ bout,    // [32]
            const float* __restrict__ dw,      // [2162]
            float* __restrict__ v,             // [64][128]
            float* __restrict__ Cout) {        // [1]
    int tid = threadIdx.x;
    for (int idx = tid; idx < 64*128; idx += 256) {
        int f = idx >> 7, k = idx & 127;
        float s = 0.f;
        #pragma unroll
        for (int j = 0; j < 32; ++j) s += W2[k*32+j] * dw[114 + f*32 + j];
        v[idx] = s;
    }
    float p = 0.f;
    for (int idx = tid; idx < 2048; idx += 256)
        p += bout[idx & 31] * dw[114 + idx];
    __shared__ float red[256];
    red[tid] = p;
    __syncthreads();
    for (int s = 128; s > 0; s >>= 1) {
        if (tid < s) red[tid] += red[tid+s];
        __syncthreads();
    }
    if (tid == 0) Cout[0] = red[0];
}

// ---------------------------------------------------------------------------
// k_emb: emb = x@embW + embB (stored in both [b,f,d] and [b,d,f] layouts);
//        liner[row] = x@linW + linB
// ---------------------------------------------------------------------------
__global__ __launch_bounds__(256)
void k_emb(const float* __restrict__ x,        // [B,F,32]
           const float* __restrict__ embW,     // [32][15]
           const float* __restrict__ embB,     // [15]
           const float* __restrict__ linW,     // [32]
           const float* __restrict__ linB,     // [1]
           float* __restrict__ emb_bfd,        // [ROWS][15]
           float* __restrict__ emb_bdf,        // [BD][64]
           float* __restrict__ liner) {        // [ROWS]
    __shared__ float xL[256*33];   // 33.8 KB
    __shared__ float wL[32*15];
    __shared__ float lwL[32];
    int tid = threadIdx.x;
    for (int i = tid; i < 480; i += 256) wL[i] = embW[i];
    if (tid < 32) lwL[tid] = linW[tid];
    const float4* xs = (const float4*)(x + (size_t)blockIdx.x * 256 * 32);
    #pragma unroll
    for (int j = 0; j < 8; ++j) {
        int f4 = tid + 256*j;
        float4 val = xs[f4];
        int row = f4 >> 3, k0 = (f4 & 7) << 2;
        xL[row*33 + k0]     = val.x;
        xL[row*33 + k0 + 1] = val.y;
        xL[row*33 + k0 + 2] = val.z;
        xL[row*33 + k0 + 3] = val.w;
    }
    __syncthreads();
    int row = blockIdx.x * 256 + tid;
    float acc[15];
    #pragma unroll
    for (int d2 = 0; d2 < 15; ++d2) acc[d2] = 0.f;
    float lin = 0.f;
    #pragma unroll
    for (int k = 0; k < 32; ++k) {
        float xv = xL[tid*33 + k];
        #pragma unroll
        for (int d2 = 0; d2 < 15; ++d2) acc[d2] += xv * wL[k*15 + d2];
        lin += xv * lwL[k];
    }
    int b = row >> 6, f = row & 63;
    #pragma unroll
    for (int d2 = 0; d2 < 15; ++d2) {
        float val = acc[d2] + embB[d2];
        emb_bfd[(size_t)row*15 + d2] = val;
        emb_bdf[(size_t)(b*15 + d2)*64 + f] = val;   // coalesced over f within wave
    }
    liner[row] = lin + linB[0];
}

// ---------------------------------------------------------------------------
// k_dnn v2.1: fused h1=relu(emb@W0+b0) -> h2=relu(h1@W1+b1) -> rdnn=h2 . v[f]
// 128 rows/block, 256 threads. GEMM: 8x8 tile, frags via ds_read_b128 from
// h1T[k][row] / w1c[k][col] (stride 128: a = 16-lane bcast banks 0/8/16/24;
// w = 256B contiguous 2-way = free). h1-compute: 4x4 tile.
// w0c DOUBLE-BUFFERED (race fix): chunk kc+1 staged during phase kc; read of
// chunk kc made visible by the top-of-loop barrier. LDS 44.5 KB -> 3 blk/CU.
// Predicted 192 -> 75-95 us, VALUBusy 65-75%, occupancy ~31-37%.
// ---------------------------------------------------------------------------
__global__ __launch_bounds__(256)
void k_dnn(const float* __restrict__ emb_bfd,  // [ROWS][15]
           const float* __restrict__ W0,       // [15][256]
           const float* __restrict__ b0,       // [256]
           const float* __restrict__ W1,       // [256][128]
           const float* __restrict__ b1,       // [128]
           const float* __restrict__ v,        // [64][128]
           float* __restrict__ rdnn) {         // [ROWS]
    __shared__ float embL[128*15];    //  7.5 KB  linear [row][q]
    __shared__ float w0c[2][15*33];   //  4.0 KB  W0 chunk [q][c] pad 33, dbuf
    __shared__ float b0L[256];        //  1.0 KB
    __shared__ float h1T[32*128];     // 16.0 KB  h1T[k][row]
    __shared__ float w1c[32*128];     // 16.0 KB  w1c[k][col]
    int tid = threadIdx.x;
    int rows0 = blockIdx.x * 128;

    // prologue: stage embL (480 float4, linear), b0L, and w0c chunk 0
    {
        const float4* src = (const float4*)(emb_bfd + (size_t)rows0*15);
        float4* dst = (float4*)embL;
        if (tid < 240) { dst[tid] = src[tid]; dst[tid+240] = src[tid+240]; }
        b0L[tid] = b0[tid];
        if (tid < 120) {
            int q = tid >> 3, c4 = (tid & 7) * 4;
            float4 vv = *(const float4*)(W0 + q*256 + 0*32 + c4);
            w0c[0][q*33 + c4]     = vv.x;
            w0c[0][q*33 + c4 + 1] = vv.y;
            w0c[0][q*33 + c4 + 2] = vv.z;
            w0c[0][q*33 + c4 + 3] = vv.w;
        }
    }

    float acc[8][8];
    #pragma unroll
    for (int i = 0; i < 8; ++i)
        #pragma unroll
        for (int j = 0; j < 8; ++j) acc[i][j] = 0.f;

    int rg2 = tid >> 3, cg = tid & 7;   // h1-compute: rows rg2*4..+3, cols cg*4..+3
    int rt = tid >> 4, ct = tid & 15;   // GEMM: rows rt*8..+7, cols ct*4..+3 & +64
    int c0 = ct * 4;

    for (int kc = 0; kc < 8; ++kc) {
        __syncthreads();   // h1T/w1c reads done; w0c[kc&1] (prev iter) visible
        // stage NEXT w0 chunk into the other buffer (read next iteration)
        if (kc < 7 && tid < 120) {
            int q = tid >> 3, c4 = (tid & 7) * 4;
            float4 vv = *(const float4*)(W0 + q*256 + (kc+1)*32 + c4);
            float* wb = w0c[(kc+1) & 1];
            wb[q*33 + c4]     = vv.x;
            wb[q*33 + c4 + 1] = vv.y;
            wb[q*33 + c4 + 2] = vv.z;
            wb[q*33 + c4 + 3] = vv.w;
        }
        // stage w1 chunk [32][128] (coalesced float4 both sides)
        #pragma unroll
        for (int it = 0; it < 4; ++it) {
            int idx = tid + it*256;          // 0..1023 float4s
            int k = idx >> 5, c4 = (idx & 31) * 4;
            float4 vv = *(const float4*)(W1 + kc*4096 + k*128 + c4);
            *(float4*)&w1c[k*128 + c4] = vv;
        }
        // h1-compute: 4x4 tile from w0c[kc&1] (staged last iteration/prologue)
        {
            const float* w0b = w0c[kc & 1];
            float hacc[4][4];
            #pragma unroll
            for (int i = 0; i < 4; ++i)
                #pragma unroll
                for (int j = 0; j < 4; ++j) hacc[i][j] = 0.f;
            #pragma unroll
            for (int q = 0; q < 15; ++q) {
                float e[4], w[4];
                #pragma unroll
                for (int i = 0; i < 4; ++i) e[i] = embL[(rg2*4 + i)*15 + q];
                #pragma unroll
                for (int j = 0; j < 4; ++j) w[j] = w0b[q*33 + cg*4 + j];
                #pragma unroll
                for (int i = 0; i < 4; ++i)
                    #pragma unroll
                    for (int j = 0; j < 4; ++j) hacc[i][j] += e[i]*w[j];
            }
            #pragma unroll
            for (int j = 0; j < 4; ++j) {
                float bbj = b0L[kc*32 + cg*4 + j];
                float4 hv;
                hv.x = fmaxf(hacc[0][j] + bbj, 0.f);
                hv.y = fmaxf(hacc[1][j] + bbj, 0.f);
                hv.z = fmaxf(hacc[2][j] + bbj, 0.f);
                hv.w = fmaxf(hacc[3][j] + bbj, 0.f);
                *(float4*)&h1T[(cg*4 + j)*128 + rg2*4] = hv;
            }
        }
        __syncthreads();
        // GEMM: 32 k-steps, 4 x ds_read_b128 per step
        #pragma unroll 4
        for (int k = 0; k < 32; ++k) {
            float4 a0 = *(const float4*)&h1T[k*128 + rt*8];
            float4 a1 = *(const float4*)&h1T[k*128 + rt*8 + 4];
            float4 w0v = *(const float4*)&w1c[k*128 + c0];
            float4 w1v = *(const float4*)&w1c[k*128 + c0 + 64];
            float a[8] = {a0.x,a0.y,a0.z,a0.w,a1.x,a1.y,a1.z,a1.w};
            float w[8] = {w0v.x,w0v.y,w0v.z,w0v.w,w1v.x,w1v.y,w1v.z,w1v.w};
            #pragma unroll
            for (int i = 0; i < 8; ++i)
                #pragma unroll
                for (int j = 0; j < 8; ++j) acc[i][j] += a[i]*w[j];
        }
    }
    // epilogue: relu(+b1), dot with v[f], reduce over 16 ct-lanes
    float b1v[8];
    #pragma unroll
    for (int j = 0; j < 4; ++j) { b1v[j] = b1[c0 + j]; b1v[j+4] = b1[c0 + 64 + j]; }
    #pragma unroll
    for (int i = 0; i < 8; ++i) {
        int lrow = rt*8 + i;
        int f = lrow & 63;   // rows0 is a multiple of 128
        float p = 0.f;
        #pragma unroll
        for (int j = 0; j < 4; ++j) {
            float h2a = fmaxf(acc[i][j]   + b1v[j],   0.f);
            float h2b = fmaxf(acc[i][j+4] + b1v[j+4], 0.f);
            p += h2a * v[f*128 + c0 + j];
            p += h2b * v[f*128 + c0 + 64 + j];
        }
        p += __shfl_xor(p, 1, 64);
        p += __shfl_xor(p, 2, 64);
        p += __shfl_xor(p, 4, 64);
        p += __shfl_xor(p, 8, 64);
        if (ct == 0) rdnn[rows0 + lrow] = p;
    }
}

// ---------------------------------------------------------------------------
// k_cin v3 (unchanged): 32 rows/block, 4x20 tile, vector LDS, 1-shuffle epi.
// ---------------------------------------------------------------------------
__global__ __launch_bounds__(256)
void k_cin(const float* __restrict__ emb_bdf,  // [BD][64]
           const float* __restrict__ cw0,      // [4096][10]
           const float* __restrict__ cw1,      // [640][10]
           const float* __restrict__ cw2,
           const float* __restrict__ cw3,
           const float* __restrict__ cw4,
           float* __restrict__ hi_ws) {        // [5][BD][10]
    __shared__ float EL[64*36];    //  9.2 KB  E^T[field][row], rows 0..31
    __shared__ float AB[64*102];   // 26.1 KB  A-chunk [f][80|100+2] / PB [32][162]
    __shared__ float HT[10*36];    //  1.4 KB  h^T[n][row]
    int tid = threadIdx.x;
    int rt = tid >> 5, ct = tid & 31;
    int rows0 = blockIdx.x * 32;
    const int fp1 = ct, fp2 = ct + 32;

    {
        int f = tid & 63, rb = tid >> 6;
        #pragma unroll
        for (int it = 0; it < 8; ++it) {
            int r = rb + it*4;
            EL[f*36 + r] = emb_bdf[(size_t)(rows0 + r)*64 + f];
        }
    }

    float acc[4][20];
    #pragma unroll
    for (int i = 0; i < 4; ++i)
        #pragma unroll
        for (int j = 0; j < 20; ++j) acc[i][j] = 0.f;

    #define CIN_EPI(LIDX)                                                       \
    {                                                                           \
        __syncthreads(); /* k-loop reads of AB done; AB becomes PB */           \
        float ef1[4], ef2[4];                                                   \
        *(float4*)&ef1[0] = *(const float4*)&EL[fp1*36 + rt*4];                 \
        *(float4*)&ef2[0] = *(const float4*)&EL[fp2*36 + rt*4];                 \
        _Pragma("unroll")                                                       \
        for (int i = 0; i < 4; ++i) {                                           \
            _Pragma("unroll")                                                   \
            for (int n = 0; n < 10; ++n) {                                      \
                float p = ef1[i]*acc[i][n] + ef2[i]*acc[i][10+n];               \
                p += __shfl_xor(p, 16, 64);                                     \
                acc[i][n] = p;                                                  \
            }                                                                   \
        }                                                                       \
        if (ct < 16) {                                                          \
            _Pragma("unroll")                                                   \
            for (int i = 0; i < 4; ++i) {                                       \
                float2* pb = (float2*)&AB[(rt*4 + i)*162 + ct*10];              \
                _Pragma("unroll")                                               \
                for (int t = 0; t < 5; ++t)                                     \
                    pb[t] = make_float2(acc[i][t*2], acc[i][t*2+1]);            \
            }                                                                   \
        }                                                                       \
        __syncthreads();                                                        \
        for (int o = tid; o < 320; o += 256) {                                  \
            int r2 = o / 10, n2 = o - r2*10;                                    \
            float s = 0.f;                                                      \
            _Pragma("unroll")                                                   \
            for (int c2 = 0; c2 < 16; ++c2) s += AB[r2*162 + c2*10 + n2];       \
            HT[n2*36 + r2] = s;                                                 \
            hi_ws[((size_t)(LIDX)*BD_ + rows0 + r2)*10 + n2] = s;               \
        }                                                                       \
    }

    for (int c = 0; c < 8; ++c) {
        __syncthreads();
        {
            int f = tid >> 2, q = tid & 3;
            const float4* src = (const float4*)(cw0 + f*640 + c*80);
            #pragma unroll
            for (int t = 0; t < 5; ++t) {
                int idx = q + t*4;
                float4 vv = src[idx];
                float2* dst = (float2*)&AB[f*82 + idx*4];
                dst[0] = make_float2(vv.x, vv.y);
                dst[1] = make_float2(vv.z, vv.w);
            }
        }
        __syncthreads();
        #pragma unroll
        for (int gl = 0; gl < 8; ++gl) {
            int g = c*8 + gl;
            float e4[4];
            *(float4*)&e4[0] = *(const float4*)&EL[g*36 + rt*4];
            float2 a1[5];
            #pragma unroll
            for (int t = 0; t < 5; ++t)
                a1[t] = *(const float2*)&AB[fp1*82 + gl*10 + t*2];
            #pragma unroll
            for (int i = 0; i < 4; ++i) {
                float e = e4[i];
                #pragma unroll
                for (int t = 0; t < 5; ++t) {
                    acc[i][t*2]   += e * a1[t].x;
                    acc[i][t*2+1] += e * a1[t].y;
                }
            }
            float2 a2[5];
            #pragma unroll
            for (int t = 0; t < 5; ++t)
                a2[t] = *(const float2*)&AB[fp2*82 + gl*10 + t*2];
            #pragma unroll
            for (int i = 0; i < 4; ++i) {
                float e = e4[i];
                #pragma unroll
                for (int t = 0; t < 5; ++t) {
                    acc[i][10+t*2]   += e * a2[t].x;
                    acc[i][10+t*2+1] += e * a2[t].y;
                }
            }
        }
    }
    CIN_EPI(0)

    for (int l = 1; l < 5; ++l) {
        const float* cw = (l==1) ? cw1 : (l==2) ? cw2 : (l==3) ? cw3 : cw4;
        __syncthreads();
        {
            int f = tid >> 2, q = tid & 3;
            const float4* src = (const float4*)(cw + f*100);
            for (int idx = q; idx < 25; idx += 4) {
                float4 vv = src[idx];
                float2* dst = (float2*)&AB[f*102 + idx*4];
                dst[0] = make_float2(vv.x, vv.y);
                dst[1] = make_float2(vv.z, vv.w);
            }
        }
        #pragma unroll
        for (int i = 0; i < 4; ++i)
            #pragma unroll
            for (int j = 0; j < 20; ++j) acc[i][j] = 0.f;
        __syncthreads();
        #pragma unroll
        for (int g = 0; g < 10; ++g) {
            float e4[4];
            *(float4*)&e4[0] = *(const float4*)&HT[g*36 + rt*4];
            float2 a1[5];
            #pragma unroll
            for (int t = 0; t < 5; ++t)
                a1[t] = *(const float2*)&AB[fp1*102 + g*10 + t*2];
            #pragma unroll
            for (int i = 0; i < 4; ++i) {
                float e = e4[i];
                #pragma unroll
                for (int t = 0; t < 5; ++t) {
                    acc[i][t*2]   += e * a1[t].x;
                    acc[i][t*2+1] += e * a1[t].y;
                }
            }
            float2 a2[5];
            #pragma unroll
            for (int t = 0; t < 5; ++t)
                a2[t] = *(const float2*)&AB[fp2*102 + g*10 + t*2];
            #pragma unroll
            for (int i = 0; i < 4; ++i) {
                float e = e4[i];
                #pragma unroll
                for (int t = 0; t < 5; ++t) {
                    acc[i][10+t*2]   += e * a2[t].x;
                    acc[i][10+t*2+1] += e * a2[t].y;
                }
            }
        }
        CIN_EPI(l)
    }
    #undef CIN_EPI
}

// ---------------------------------------------------------------------------
// k_combine: out[b] = sum_f liner*dw + sum cin*dw + sum_f rdnn + db + C
// ---------------------------------------------------------------------------
__global__ __launch_bounds__(64)
void k_combine(const float* __restrict__ liner,   // [ROWS]
               const float* __restrict__ rdnn,    // [ROWS]
               const float* __restrict__ hi_ws,   // [5][BD][10]
               const float* __restrict__ dw,      // [2162]
               const float* __restrict__ db,      // [1]
               const float* __restrict__ Cc,      // [1]
               float* __restrict__ out) {         // [B]
    int b = blockIdx.x, t = threadIdx.x;
    float s = liner[b*64+t]*dw[t] + rdnn[b*64+t];
    for (int i = t; i < 750; i += 64) {
        int ld = i / 10, n = i - ld*10;
        int l = ld / 15, d = ld - l*15;
        s += hi_ws[((size_t)l*BD_ + b*15 + d)*10 + n] * dw[64 + l*10 + n];
    }
    #pragma unroll
    for (int m = 1; m < 64; m <<= 1) s += __shfl_xor(s, m, 64);
    if (t == 0) out[b] = s + db[0] + Cc[0];
}

// ---------------------------------------------------------------------------
extern "C" void kernel_launch(void* const* d_in, const int* in_sizes, int n_in,
                              void* d_out, int out_size, void* d_ws, size_t ws_size,
                              hipStream_t stream) {
    const float* x    = (const float*)d_in[0];
    const float* embW = (const float*)d_in[1];
    const float* embB = (const float*)d_in[2];
    const float* linW = (const float*)d_in[3];
    const float* linB = (const float*)d_in[4];
    const float* W0   = (const float*)d_in[5];
    const float* b0   = (const float*)d_in[6];
    const float* W1   = (const float*)d_in[7];
    const float* b1   = (const float*)d_in[8];
    const float* W2   = (const float*)d_in[9];
    const float* bout = (const float*)d_in[10];
    const float* cw0  = (const float*)d_in[11];
    const float* cw1  = (const float*)d_in[12];
    const float* cw2  = (const float*)d_in[13];
    const float* cw3  = (const float*)d_in[14];
    const float* cw4  = (const float*)d_in[15];
    const float* dw   = (const float*)d_in[16];
    const float* db   = (const float*)d_in[17];

    float* ws = (float*)d_ws;
    float* emb_bfd = ws;                   // 1,966,080 floats
    float* emb_bdf = ws + 1966080;         // 1,966,080
    float* liner   = ws + 3932160;         //   131,072
    float* rdnn    = ws + 4063232;         //   131,072
    float* hi_ws   = ws + 4194304;         // 1,536,000
    float* v       = ws + 5730304;         //     8,192
    float* Cc      = ws + 5738496;         //         1  (total ~22.96 MB)
    float* out = (float*)d_out;

    k_prep<<<1, 256, 0, stream>>>(W2, bout, dw, v, Cc);
    k_emb<<<512, 256, 0, stream>>>(x, embW, embB, linW, linB, emb_bfd, emb_bdf, liner);
    k_dnn<<<1024, 256, 0, stream>>>(emb_bfd, W0, b0, W1, b1, v, rdnn);
    k_cin<<<960, 256, 0, stream>>>(emb_bdf, cw0, cw1, cw2, cw3, cw4, hi_ws);
    k_combine<<<2048, 64, 0, stream>>>(liner, rdnn, hi_ws, dw, db, Cc, out);
}